// Round 6
// baseline (199.304 us; speedup 1.0000x reference)
//
#include <hip/hip_runtime.h>
#include <math.h>
#include <utility>

#define DEV __device__ __forceinline__

// ================= compile-time CG tables =================
// All Wigner/CG math at compile time. cg_r consumed as constexpr immediates
// (sparsity folded, ~75% of vr FMAs eliminated); cg_l copied to ws and read
// through an OPAQUE runtime pointer (R3: const-folding BOTH sides regressed
// codegen; hybrid keeps code small and cgl on the scalar pipe).

constexpr double FC[14] = {1.,1.,2.,6.,24.,120.,720.,5040.,40320.,362880.,
                           3628800.,39916800.,479001600.,6227020800.};

constexpr double csqrt(double x) {
  if (x <= 0.0) return 0.0;
  double g = x > 1.0 ? x : 1.0;
  double p = 0.0;
  for (int i = 0; i < 64 && g != p; ++i) { p = g; g = 0.5 * (g + x / g); }
  return g;
}

constexpr int cimax(int a, int b) { return a > b ? a : b; }
constexpr int cimin(int a, int b) { return a < b ? a : b; }

constexpr double su2cg_c(int j1, int m1, int j2, int m2, int j3, int m3) {
  if (m3 != m1 + m2) return 0.0;
  int vmin = cimax(cimax(-j1 + j2 + m3, -j1 + m1), 0);
  int vmax = cimin(cimin(j2 + j3 + m1, j3 - j1 + j2), j3 + m3);
  if (vmax < vmin) return 0.0;
  double C = csqrt((2.0 * j3 + 1.0)
      * FC[j3 + j1 - j2] * FC[j3 - j1 + j2] * FC[j1 + j2 - j3]
      * FC[j3 + m3] * FC[j3 - m3]
      / (FC[j1 + j2 + j3 + 1] * FC[j1 - m1] * FC[j1 + m1]
         * FC[j2 - m2] * FC[j2 + m2]));
  double S = 0.0;
  for (int v = vmin; v <= vmax; ++v) {
    double term = FC[j2 + j3 + m1 - v] * FC[j1 - m1 + v]
        / (FC[v] * FC[j3 - j1 + j2 - v] * FC[j3 + m3 - v]
           * FC[v + j1 - j2 - m3]);
    S += ((v + j2 + m2) & 1) ? -term : term;
  }
  return C * S;
}

constexpr int nqcol(int l, int c, int* rows, double* vx, double* vy) {
  const double r2 = 0.70710678118654752440;
  double sg = (l % 4 == 2) ? -1.0 : 1.0;
  if (c == l) { rows[0] = l; vx[0] = sg; vy[0] = 0.0; return 1; }
  if (c > l) {
    int mm = c - l;
    double par = (mm & 1) ? -1.0 : 1.0;
    rows[0] = l - mm; vx[0] = sg * r2;       vy[0] = 0.0;
    rows[1] = l + mm; vx[1] = sg * par * r2; vy[1] = 0.0;
    return 2;
  }
  int mm = l - c;
  double par = (mm & 1) ? -1.0 : 1.0;
  rows[0] = l - mm; vx[0] = 0.0; vy[0] = -sg * r2;
  rows[1] = l + mm; vx[1] = 0.0; vy[1] = sg * par * r2;
  return 2;
}

constexpr int KCL [11] = {0,0,0, 2,2,2,2, 4,4,4,4};
constexpr int KCL1[11] = {0,2,4, 0,2,2,4, 0,2,2,4};
constexpr int KCL2[11] = {0,2,4, 2,2,4,4, 4,2,4,4};
constexpr int KOFF[11] = {0,1,26,107,132,257,482,887,968,1193,1598};

struct CCGT { double v[11][81]; };
constexpr CCGT make_ccg() {
  CCGT z = {};
  for (int c = 0; c < 11; ++c) {
    int l = KCL[c], l1 = KCL1[c], l2 = KCL2[c];
    int D1 = 2 * l1 + 1, D2 = 2 * l2 + 1;
    for (int a = 0; a < D1; ++a)
      for (int b = 0; b < D2; ++b) {
        int m1 = a - l1, m2 = b - l2, m3 = m1 + m2;
        z.v[c][a * D2 + b] =
            (m3 >= -l && m3 <= l) ? su2cg_c(l1, m1, l2, m2, l, m3) : 0.0;
      }
  }
  return z;
}
constexpr CCGT CCG = make_ccg();

struct CGTab { float r[2327]; float l[2327]; };
constexpr CGTab make_tables(const CCGT& cc) {
  CGTab t = {};
  for (int c = 0; c < 11; ++c) {
    int l = KCL[c], l1 = KCL1[c], l2 = KCL2[c];
    int D = 2 * l + 1, D1 = 2 * l1 + 1, D2 = 2 * l2 + 1;
    int n = D * D1 * D2, off = KOFF[c];
    double wbuf[729] = {};
    for (int e = 0; e < n; ++e) {
      int k = e % D; int ab = e / D; int b = ab % D2; int a = ab / D2;
      int r1[2] = {}, r2[2] = {}, r3[2] = {};
      double x1[2] = {}, y1[2] = {}, x2[2] = {}, y2[2] = {}, x3[2] = {}, y3[2] = {};
      int n1 = nqcol(l1, a, r1, x1, y1);
      int n2 = nqcol(l2, b, r2, x2, y2);
      int n3 = nqcol(l, k, r3, x3, y3);
      double s = 0.0;
      for (int i1 = 0; i1 < n1; ++i1)
        for (int i2 = 0; i2 < n2; ++i2) {
          double px = x1[i1] * x2[i2] - y1[i1] * y2[i2];
          double py = x1[i1] * y2[i2] + y1[i1] * x2[i2];
          int m12 = (r1[i1] - l1) + (r2[i2] - l2);
          for (int i3 = 0; i3 < n3; ++i3) {
            if (r3[i3] - l != m12) continue;
            s += (px * x3[i3] + py * y3[i3]) * cc.v[c][r1[i1] * D2 + r2[i2]];
          }
        }
      wbuf[e] = s;
    }
    double ss = 0.0;
    for (int e = 0; e < n; ++e) ss += wbuf[e] * wbuf[e];
    double inv = (l1 != l2 ? 1.41421356237309504880 : 1.0) / csqrt(ss);
    for (int o = 0; o < n; ++o) {
      int k = o / (D1 * D2), tt = o % (D1 * D2);
      int a = tt % D1, b = tt / D1;   // w[a][b][k]
      int x = tt / D2, y = tt % D2;
      double val = wbuf[(a * D2 + b) * D + k] * inv;
      t.r[off + o] = (float)val;                          // k*D1*D2 + x*D2 + y
      t.l[off + k * (D1 * D2) + y * D1 + x] = (float)val; // k*D1*D2 + y*D1 + x
    }
  }
  return t;
}
constexpr CGTab GT = make_tables(CCG);
__constant__ CGTab G = GT;

// setup: block 0 copies cg_l -> ws; block 1 feats passthrough. ~2 us.
__global__ void setup_copy(float* __restrict__ ws,
                           const float* __restrict__ feats,
                           float* __restrict__ out) {
  int tid = threadIdx.x;
  if (blockIdx.x == 0) {
    for (int i = tid; i < 2327; i += 256) ws[i] = G.l[i];
  } else {
    for (int i = tid; i < 1024; i += 256) {
      int n = i >> 6, j = i & 63;
      out[7012352 + n * 12352 + j] = feats[i];
    }
  }
}

// ================= sparse combo machinery =================
// vr[k] = sum_i Brow[i] * cg_r[k][P][i], CG constexpr, zeros folded out.

template<int OFF, int D1, int D2, int P, int K>
constexpr bool vr_row_nz() {
  for (int i = 0; i < D2; ++i)
    if (GT.r[OFF + K * D1 * D2 + P * D2 + i] != 0.0f) return true;
  return false;
}

template<int OFF, int D1, int D2, int P, int K, int I>
DEV void vr_step(const float* __restrict__ Brow, float& s) {
  constexpr float c = GT.r[OFF + K * D1 * D2 + P * D2 + I];
  if constexpr (c != 0.0f) s = fmaf(Brow[I], c, s);
}

template<int OFF, int D1, int D2, int P, int K, int... Is>
DEV float vr_k(const float* __restrict__ Brow, std::integer_sequence<int, Is...>) {
  float s = 0.f;
  (vr_step<OFF, D1, D2, P, K, Is>(Brow, s), ...);
  return s;
}

template<int OFF, int D, int D1, int D2, int P, int... Ks>
DEV void vr_all(const float* __restrict__ Brow, float* __restrict__ vr,
                std::integer_sequence<int, Ks...>) {
  ((vr[Ks] = vr_k<OFF, D1, D2, P, Ks>(Brow, std::make_integer_sequence<int, D2>{})), ...);
}

template<int OFF, int D, int D1, int D2, int P, int K1, int K2>
DEV void acc_one(const float* __restrict__ vl, const float* __restrict__ vr,
                 float* __restrict__ acc) {
  if constexpr (vr_row_nz<OFF, D1, D2, P, K2>())
    acc[K1 * D + K2] = fmaf(vl[K1], vr[K2], acc[K1 * D + K2]);
}

template<int OFF, int D, int D1, int D2, int P, int K1, int... K2s>
DEV void acc_row(const float* __restrict__ vl, const float* __restrict__ vr,
                 float* __restrict__ acc, std::integer_sequence<int, K2s...>) {
  (acc_one<OFF, D, D1, D2, P, K1, K2s>(vl, vr, acc), ...);
}

template<int OFF, int D, int D1, int D2, int P, int... K1s>
DEV void acc_all(const float* __restrict__ vl, const float* __restrict__ vr,
                 float* __restrict__ acc, std::integer_sequence<int, K1s...>) {
  (acc_row<OFF, D, D1, D2, P, K1s>(vl, vr, acc, std::make_integer_sequence<int, D>{}), ...);
}

// ---- multi-p bodies (R6): one q-loop per combo; Brow ds_reads and cgl
// s_loads issued ONCE per q and CSE-shared across the unrolled p's. ----

template<int C, int D, int D1, int D2, int NP, int P0, int PP>
DEV void mp_one_p(const float* __restrict__ cglws, const float (&Acol)[NP][D1],
                  const float* __restrict__ Brow, int q, float* __restrict__ acc) {
  constexpr int OFF = KOFF[C];
  float vl[D];
  #pragma unroll
  for (int k = 0; k < D; ++k) {
    float s = 0.f;
    #pragma unroll
    for (int j = 0; j < D1; ++j)
      s = fmaf(Acol[PP][j], cglws[k * D1 * D2 + q * D1 + j], s);
    vl[k] = s;
  }
  float vr[D];
  vr_all<OFF, D, D1, D2, P0 + PP>(Brow, vr, std::make_integer_sequence<int, D>{});
  acc_all<OFF, D, D1, D2, P0 + PP>(vl, vr, acc, std::make_integer_sequence<int, D>{});
}

template<int C, int D, int D1, int D2, int NP, int P0, int... PPs>
DEV void mp_q_iter(const float* __restrict__ cglws, const float (&Acol)[NP][D1],
                   const float* __restrict__ Brow, int q, float* __restrict__ acc,
                   std::integer_sequence<int, PPs...>) {
  (mp_one_p<C, D, D1, D2, NP, P0, PPs>(cglws, Acol, Brow, q, acc), ...);
}

// combo C over p in [P0, P0+NP)
template<int C, int D, int D1, int D2, int P0, int NP>
DEV void combo_mp(const float* __restrict__ ws, const float* __restrict__ A,
                  const float* __restrict__ B, int lane, float* __restrict__ acc) {
  const float* cglws = ws + KOFF[C];
  float Acol[NP][D1];
  #pragma unroll
  for (int pp = 0; pp < NP; ++pp) {
    #pragma unroll
    for (int j = 0; j < D1; ++j)
      Acol[pp][j] = A[(j * D1 + P0 + pp) * 65 + lane];
  }
  #pragma unroll 1
  for (int q = 0; q < D2; ++q) {
    float Brow[D2];
    #pragma unroll
    for (int i = 0; i < D2; ++i) Brow[i] = B[(q * D2 + i) * 65 + lane];
    mp_q_iter<C, D, D1, D2, NP, P0>(cglws, Acol, Brow, q, acc,
                                    std::make_integer_sequence<int, NP>{});
  }
}

// ================= main compute =================
// LDS layout: lds[elem*65 + site], elem: 0 = rh0, 1..25 = rh2, 26..106 = rh4
// bounds(256,2): measured-good. (256,4) spilled (R2); (256,3) regressed
// codegen 140->230 us (R3). Do not touch.
__global__ __launch_bounds__(256, 2)
void quad_main(const float* __restrict__ rh0, const float* __restrict__ rh2,
               const float* __restrict__ rh4, const float* __restrict__ ws,
               float* __restrict__ out) {
  __shared__ float lds[107 * 65];
  const int tid = threadIdx.x;
  const int lane = tid & 63;
  const int wave = tid >> 6;
  const int blk = blockIdx.x;
  const int site0 = blk * 64;

  // stage 64 sites into LDS (coalesced global reads, conflict-free LDS writes)
  if (tid < 64) lds[tid] = rh0[site0 + tid];
  for (int f = tid; f < 1600; f += 256) {
    int s = f / 25, e = f - s * 25;
    lds[(1 + e) * 65 + s] = rh2[site0 * 25 + f];
  }
  for (int f = tid; f < 5184; f += 256) {
    int s = f / 81, e = f - s * 81;
    lds[(26 + e) * 65 + s] = rh4[site0 * 81 + f];
  }
  __syncthreads();

  const float* r0 = lds;
  const float* r2l = lds + 65;
  const float* r4l = lds + 26 * 65;

  float acc0[1] = {0.f};
  float acc2[25], acc4[81];
  #pragma unroll
  for (int i = 0; i < 25; ++i) acc2[i] = 0.f;
  #pragma unroll
  for (int i = 0; i < 81; ++i) acc4[i] = 0.f;

  // p-split across waves; sparse FMA/wave ~ 9720 / 9180 / 9200 / 9250
  if (wave == 0) {
    combo_mp<10,9,9,9,0,6>(ws, r4l, r4l, lane, acc4);   // (4,4,4) p0-5
  } else if (wave == 1) {
    combo_mp<6,5,9,9,0,9>(ws, r4l, r4l, lane, acc2);    // (2,4,4)
    combo_mp<5,5,5,9,0,5>(ws, r2l, r4l, lane, acc2);    // (2,2,4)
  } else if (wave == 2) {
    combo_mp<9,9,5,9,0,5>(ws, r2l, r4l, lane, acc4);    // (4,2,4)
    combo_mp<8,9,5,5,0,4>(ws, r2l, r2l, lane, acc4);    // (4,2,2) p0-3
  } else {
    combo_mp<10,9,9,9,6,3>(ws, r4l, r4l, lane, acc4);   // (4,4,4) p6-8
    combo_mp<8,9,5,5,4,1>(ws, r2l, r2l, lane, acc4);    // (4,2,2) p4
    combo_mp<7,9,1,9,0,1>(ws, r0, r4l, lane, acc4);     // (4,0,4)
    combo_mp<4,5,5,5,0,5>(ws, r2l, r2l, lane, acc2);    // (2,2,2)
    combo_mp<3,5,1,5,0,1>(ws, r0, r2l, lane, acc2);     // (2,0,2)
    combo_mp<2,1,9,9,0,9>(ws, r4l, r4l, lane, acc0);    // (0,4,4)
    combo_mp<1,1,5,5,0,5>(ws, r2l, r2l, lane, acc0);    // (0,2,2)
    combo_mp<0,1,1,1,0,1>(ws, r0, r0, lane, acc0);      // (0,0,0)
  }

  // merge partial accumulators through LDS (staging data is dead now)
  __syncthreads();
  if (wave == 0) {
    lds[lane] = acc0[0];
    #pragma unroll
    for (int e = 0; e < 25; ++e) lds[(1 + e) * 65 + lane] = acc2[e];
    #pragma unroll
    for (int e = 0; e < 81; ++e) lds[(26 + e) * 65 + lane] = acc4[e];
  }
  __syncthreads();
  if (wave == 1) {
    lds[lane] += acc0[0];
    #pragma unroll
    for (int e = 0; e < 25; ++e) lds[(1 + e) * 65 + lane] += acc2[e];
    #pragma unroll
    for (int e = 0; e < 81; ++e) lds[(26 + e) * 65 + lane] += acc4[e];
  }
  __syncthreads();
  if (wave == 2) {
    lds[lane] += acc0[0];
    #pragma unroll
    for (int e = 0; e < 25; ++e) lds[(1 + e) * 65 + lane] += acc2[e];
    #pragma unroll
    for (int e = 0; e < 81; ++e) lds[(26 + e) * 65 + lane] += acc4[e];
  }
  __syncthreads();
  if (wave == 3) {
    lds[lane] += acc0[0];
    #pragma unroll
    for (int e = 0; e < 25; ++e) lds[(1 + e) * 65 + lane] += acc2[e];
    #pragma unroll
    for (int e = 0; e < 81; ++e) lds[(26 + e) * 65 + lane] += acc4[e];
  }
  __syncthreads();

  // coalesced stores: rh_n[0] | rh_n[2] | rh_n[4]
  if (tid < 64) out[site0 + tid] = lds[tid];
  for (int f = tid; f < 1600; f += 256) {
    int s = f / 25, e = f - s * 25;
    out[65536 + blk * 1600 + f] = lds[(1 + e) * 65 + s];
  }
  for (int f = tid; f < 5184; f += 256) {
    int s = f / 81, e = f - s * 81;
    out[1703936 + blk * 5184 + f] = lds[(26 + e) * 65 + s];
  }

  // rotation-invariant features
  if (tid < 64) {
    int site = site0 + tid;
    int nn = site >> 12, abc = site & 4095;
    float v0 = lds[tid];
    float f0 = v0 * v0;
    float s2 = 0.f;
    #pragma unroll
    for (int e = 0; e < 25; ++e) { float v = lds[(1 + e) * 65 + tid]; s2 = fmaf(v, v, s2); }
    float s4 = 0.f;
    #pragma unroll
    for (int e = 0; e < 81; ++e) { float v = lds[(26 + e) * 65 + tid]; s4 = fmaf(v, v, s4); }
    const float PI8 = 78.95683520871486f;  // 8*pi^2
    int base = 7012352 + nn * 12352 + 64;
    out[base + abc] = PI8 * f0;
    out[base + 4096 + abc] = (PI8 / 5.f) * s2;
    out[base + 8192 + abc] = (PI8 / 9.f) * s4;
  }
}

extern "C" void kernel_launch(void* const* d_in, const int* in_sizes, int n_in,
                              void* d_out, int out_size, void* d_ws, size_t ws_size,
                              hipStream_t stream) {
  const float* rh0 = (const float*)d_in[0];
  const float* rh2 = (const float*)d_in[1];
  const float* rh4 = (const float*)d_in[2];
  const float* feats = (const float*)d_in[3];
  float* out = (float*)d_out;
  float* ws = (float*)d_ws;
  setup_copy<<<2, 256, 0, stream>>>(ws, feats, out);
  quad_main<<<1024, 256, 0, stream>>>(rh0, rh2, rh4, ws, out);
}

// Round 7
// 164.140 us; speedup vs baseline: 1.2142x; 1.2142x over previous
//
#include <hip/hip_runtime.h>
#include <math.h>
#include <utility>

#define DEV __device__ __forceinline__

// ================= compile-time CG tables =================
// All Wigner/CG math at compile time. cg_r consumed as constexpr immediates
// (sparsity folded, ~75% of vr FMAs eliminated); cg_l copied to ws and read
// through an OPAQUE runtime pointer (R3: const-folding BOTH sides regressed
// codegen; hybrid keeps code small and cgl on the scalar pipe).

constexpr double FC[14] = {1.,1.,2.,6.,24.,120.,720.,5040.,40320.,362880.,
                           3628800.,39916800.,479001600.,6227020800.};

constexpr double csqrt(double x) {
  if (x <= 0.0) return 0.0;
  double g = x > 1.0 ? x : 1.0;
  double p = 0.0;
  for (int i = 0; i < 64 && g != p; ++i) { p = g; g = 0.5 * (g + x / g); }
  return g;
}

constexpr int cimax(int a, int b) { return a > b ? a : b; }
constexpr int cimin(int a, int b) { return a < b ? a : b; }

constexpr double su2cg_c(int j1, int m1, int j2, int m2, int j3, int m3) {
  if (m3 != m1 + m2) return 0.0;
  int vmin = cimax(cimax(-j1 + j2 + m3, -j1 + m1), 0);
  int vmax = cimin(cimin(j2 + j3 + m1, j3 - j1 + j2), j3 + m3);
  if (vmax < vmin) return 0.0;
  double C = csqrt((2.0 * j3 + 1.0)
      * FC[j3 + j1 - j2] * FC[j3 - j1 + j2] * FC[j1 + j2 - j3]
      * FC[j3 + m3] * FC[j3 - m3]
      / (FC[j1 + j2 + j3 + 1] * FC[j1 - m1] * FC[j1 + m1]
         * FC[j2 - m2] * FC[j2 + m2]));
  double S = 0.0;
  for (int v = vmin; v <= vmax; ++v) {
    double term = FC[j2 + j3 + m1 - v] * FC[j1 - m1 + v]
        / (FC[v] * FC[j3 - j1 + j2 - v] * FC[j3 + m3 - v]
           * FC[v + j1 - j2 - m3]);
    S += ((v + j2 + m2) & 1) ? -term : term;
  }
  return C * S;
}

constexpr int nqcol(int l, int c, int* rows, double* vx, double* vy) {
  const double r2 = 0.70710678118654752440;
  double sg = (l % 4 == 2) ? -1.0 : 1.0;
  if (c == l) { rows[0] = l; vx[0] = sg; vy[0] = 0.0; return 1; }
  if (c > l) {
    int mm = c - l;
    double par = (mm & 1) ? -1.0 : 1.0;
    rows[0] = l - mm; vx[0] = sg * r2;       vy[0] = 0.0;
    rows[1] = l + mm; vx[1] = sg * par * r2; vy[1] = 0.0;
    return 2;
  }
  int mm = l - c;
  double par = (mm & 1) ? -1.0 : 1.0;
  rows[0] = l - mm; vx[0] = 0.0; vy[0] = -sg * r2;
  rows[1] = l + mm; vx[1] = 0.0; vy[1] = sg * par * r2;
  return 2;
}

constexpr int KCL [11] = {0,0,0, 2,2,2,2, 4,4,4,4};
constexpr int KCL1[11] = {0,2,4, 0,2,2,4, 0,2,2,4};
constexpr int KCL2[11] = {0,2,4, 2,2,4,4, 4,2,4,4};
constexpr int KOFF[11] = {0,1,26,107,132,257,482,887,968,1193,1598};

struct CCGT { double v[11][81]; };
constexpr CCGT make_ccg() {
  CCGT z = {};
  for (int c = 0; c < 11; ++c) {
    int l = KCL[c], l1 = KCL1[c], l2 = KCL2[c];
    int D1 = 2 * l1 + 1, D2 = 2 * l2 + 1;
    for (int a = 0; a < D1; ++a)
      for (int b = 0; b < D2; ++b) {
        int m1 = a - l1, m2 = b - l2, m3 = m1 + m2;
        z.v[c][a * D2 + b] =
            (m3 >= -l && m3 <= l) ? su2cg_c(l1, m1, l2, m2, l, m3) : 0.0;
      }
  }
  return z;
}
constexpr CCGT CCG = make_ccg();

struct CGTab { float r[2327]; float l[2327]; };
constexpr CGTab make_tables(const CCGT& cc) {
  CGTab t = {};
  for (int c = 0; c < 11; ++c) {
    int l = KCL[c], l1 = KCL1[c], l2 = KCL2[c];
    int D = 2 * l + 1, D1 = 2 * l1 + 1, D2 = 2 * l2 + 1;
    int n = D * D1 * D2, off = KOFF[c];
    double wbuf[729] = {};
    for (int e = 0; e < n; ++e) {
      int k = e % D; int ab = e / D; int b = ab % D2; int a = ab / D2;
      int r1[2] = {}, r2[2] = {}, r3[2] = {};
      double x1[2] = {}, y1[2] = {}, x2[2] = {}, y2[2] = {}, x3[2] = {}, y3[2] = {};
      int n1 = nqcol(l1, a, r1, x1, y1);
      int n2 = nqcol(l2, b, r2, x2, y2);
      int n3 = nqcol(l, k, r3, x3, y3);
      double s = 0.0;
      for (int i1 = 0; i1 < n1; ++i1)
        for (int i2 = 0; i2 < n2; ++i2) {
          double px = x1[i1] * x2[i2] - y1[i1] * y2[i2];
          double py = x1[i1] * y2[i2] + y1[i1] * x2[i2];
          int m12 = (r1[i1] - l1) + (r2[i2] - l2);
          for (int i3 = 0; i3 < n3; ++i3) {
            if (r3[i3] - l != m12) continue;
            s += (px * x3[i3] + py * y3[i3]) * cc.v[c][r1[i1] * D2 + r2[i2]];
          }
        }
      wbuf[e] = s;
    }
    double ss = 0.0;
    for (int e = 0; e < n; ++e) ss += wbuf[e] * wbuf[e];
    double inv = (l1 != l2 ? 1.41421356237309504880 : 1.0) / csqrt(ss);
    for (int o = 0; o < n; ++o) {
      int k = o / (D1 * D2), tt = o % (D1 * D2);
      int a = tt % D1, b = tt / D1;   // w[a][b][k]
      int x = tt / D2, y = tt % D2;
      double val = wbuf[(a * D2 + b) * D + k] * inv;
      t.r[off + o] = (float)val;                          // k*D1*D2 + x*D2 + y
      t.l[off + k * (D1 * D2) + y * D1 + x] = (float)val; // k*D1*D2 + y*D1 + x
    }
  }
  return t;
}
constexpr CGTab GT = make_tables(CCG);
__constant__ CGTab G = GT;

// setup: block 0 copies cg_l -> ws; block 1 feats passthrough. ~2 us.
__global__ void setup_copy(float* __restrict__ ws,
                           const float* __restrict__ feats,
                           float* __restrict__ out) {
  int tid = threadIdx.x;
  if (blockIdx.x == 0) {
    for (int i = tid; i < 2327; i += 256) ws[i] = G.l[i];
  } else {
    for (int i = tid; i < 1024; i += 256) {
      int n = i >> 6, j = i & 63;
      out[7012352 + n * 12352 + j] = feats[i];
    }
  }
}

// ================= sparse combo machinery =================
// vr[k] = sum_i Brow[i] * cg_r[k][P][i], CG constexpr, zeros folded out.

template<int OFF, int D1, int D2, int P, int K>
constexpr bool vr_row_nz() {
  for (int i = 0; i < D2; ++i)
    if (GT.r[OFF + K * D1 * D2 + P * D2 + i] != 0.0f) return true;
  return false;
}

template<int OFF, int D1, int D2, int P, int K, int I>
DEV void vr_step(const float* __restrict__ Brow, float& s) {
  constexpr float c = GT.r[OFF + K * D1 * D2 + P * D2 + I];
  if constexpr (c != 0.0f) s = fmaf(Brow[I], c, s);
}

template<int OFF, int D1, int D2, int P, int K, int... Is>
DEV float vr_k(const float* __restrict__ Brow, std::integer_sequence<int, Is...>) {
  float s = 0.f;
  (vr_step<OFF, D1, D2, P, K, Is>(Brow, s), ...);
  return s;
}

template<int OFF, int D, int D1, int D2, int P, int... Ks>
DEV void vr_all(const float* __restrict__ Brow, float* __restrict__ vr,
                std::integer_sequence<int, Ks...>) {
  ((vr[Ks] = vr_k<OFF, D1, D2, P, Ks>(Brow, std::make_integer_sequence<int, D2>{})), ...);
}

template<int OFF, int D, int D1, int D2, int P, int K1, int K2>
DEV void acc_one(const float* __restrict__ vl, const float* __restrict__ vr,
                 float* __restrict__ acc) {
  if constexpr (vr_row_nz<OFF, D1, D2, P, K2>())
    acc[K1 * D + K2] = fmaf(vl[K1], vr[K2], acc[K1 * D + K2]);
}

template<int OFF, int D, int D1, int D2, int P, int K1, int... K2s>
DEV void acc_row(const float* __restrict__ vl, const float* __restrict__ vr,
                 float* __restrict__ acc, std::integer_sequence<int, K2s...>) {
  (acc_one<OFF, D, D1, D2, P, K1, K2s>(vl, vr, acc), ...);
}

template<int OFF, int D, int D1, int D2, int P, int... K1s>
DEV void acc_all(const float* __restrict__ vl, const float* __restrict__ vr,
                 float* __restrict__ acc, std::integer_sequence<int, K1s...>) {
  (acc_row<OFF, D, D1, D2, P, K1s>(vl, vr, acc, std::make_integer_sequence<int, D>{}), ...);
}

// ---- multi-p bodies: one q-loop per NP-chunk; Brow ds_reads and cgl
// s_loads issued once per q, CSE-shared across the NP unrolled p's.
// R6 lesson: NP=6 spills (WRITE 28->74MB, dur 103->145). NP<=3, and only
// on waves with register headroom. Wave 3 (acc=107) stays NP=1. ----

template<int C, int D, int D1, int D2, int NP, int P0, int PP>
DEV void mp_one_p(const float* __restrict__ cglws, const float (&Acol)[NP][D1],
                  const float* __restrict__ Brow, int q, float* __restrict__ acc) {
  constexpr int OFF = KOFF[C];
  float vl[D];
  #pragma unroll
  for (int k = 0; k < D; ++k) {
    float s = 0.f;
    #pragma unroll
    for (int j = 0; j < D1; ++j)
      s = fmaf(Acol[PP][j], cglws[k * D1 * D2 + q * D1 + j], s);
    vl[k] = s;
  }
  float vr[D];
  vr_all<OFF, D, D1, D2, P0 + PP>(Brow, vr, std::make_integer_sequence<int, D>{});
  acc_all<OFF, D, D1, D2, P0 + PP>(vl, vr, acc, std::make_integer_sequence<int, D>{});
}

template<int C, int D, int D1, int D2, int NP, int P0, int... PPs>
DEV void mp_q_iter(const float* __restrict__ cglws, const float (&Acol)[NP][D1],
                   const float* __restrict__ Brow, int q, float* __restrict__ acc,
                   std::integer_sequence<int, PPs...>) {
  (mp_one_p<C, D, D1, D2, NP, P0, PPs>(cglws, Acol, Brow, q, acc), ...);
}

// combo C over p in [P0, P0+NP)
template<int C, int D, int D1, int D2, int P0, int NP>
DEV void combo_mp(const float* __restrict__ ws, const float* __restrict__ A,
                  const float* __restrict__ B, int lane, float* __restrict__ acc) {
  const float* cglws = ws + KOFF[C];
  float Acol[NP][D1];
  #pragma unroll
  for (int pp = 0; pp < NP; ++pp) {
    #pragma unroll
    for (int j = 0; j < D1; ++j)
      Acol[pp][j] = A[(j * D1 + P0 + pp) * 65 + lane];
  }
  #pragma unroll 1
  for (int q = 0; q < D2; ++q) {
    float Brow[D2];
    #pragma unroll
    for (int i = 0; i < D2; ++i) Brow[i] = B[(q * D2 + i) * 65 + lane];
    mp_q_iter<C, D, D1, D2, NP, P0>(cglws, Acol, Brow, q, acc,
                                    std::make_integer_sequence<int, NP>{});
  }
}

// ================= main compute =================
// LDS layout: lds[elem*65 + site], elem: 0 = rh0, 1..25 = rh2, 26..106 = rh4
// bounds(256,2): measured-good. (256,4) spilled (R2); (256,3) regressed
// codegen 140->230 us (R3). Do not touch.
__global__ __launch_bounds__(256, 2)
void quad_main(const float* __restrict__ rh0, const float* __restrict__ rh2,
               const float* __restrict__ rh4, const float* __restrict__ ws,
               float* __restrict__ out) {
  __shared__ float lds[107 * 65];
  const int tid = threadIdx.x;
  const int lane = tid & 63;
  const int wave = tid >> 6;
  const int blk = blockIdx.x;
  const int site0 = blk * 64;

  // stage 64 sites into LDS (coalesced global reads, conflict-free LDS writes)
  if (tid < 64) lds[tid] = rh0[site0 + tid];
  for (int f = tid; f < 1600; f += 256) {
    int s = f / 25, e = f - s * 25;
    lds[(1 + e) * 65 + s] = rh2[site0 * 25 + f];
  }
  for (int f = tid; f < 5184; f += 256) {
    int s = f / 81, e = f - s * 81;
    lds[(26 + e) * 65 + s] = rh4[site0 * 81 + f];
  }
  __syncthreads();

  const float* r0 = lds;
  const float* r2l = lds + 65;
  const float* r4l = lds + 26 * 65;

  float acc0[1] = {0.f};
  float acc2[25], acc4[81];
  #pragma unroll
  for (int i = 0; i < 25; ++i) acc2[i] = 0.f;
  #pragma unroll
  for (int i = 0; i < 81; ++i) acc4[i] = 0.f;

  // p-split across waves (sparse FMA/wave ~ 9720/9180/9200/9250).
  // NP chunking per-wave by register headroom: w0 NP=2 (acc 81),
  // w1 NP=3 (acc 25), w2 NP=2 (acc 81), w3 NP=1 (acc 107 -- R2 danger).
  if (wave == 0) {
    combo_mp<10,9,9,9,0,2>(ws, r4l, r4l, lane, acc4);   // (4,4,4) p0-1
    combo_mp<10,9,9,9,2,2>(ws, r4l, r4l, lane, acc4);   // (4,4,4) p2-3
    combo_mp<10,9,9,9,4,2>(ws, r4l, r4l, lane, acc4);   // (4,4,4) p4-5
  } else if (wave == 1) {
    combo_mp<6,5,9,9,0,3>(ws, r4l, r4l, lane, acc2);    // (2,4,4) p0-2
    combo_mp<6,5,9,9,3,3>(ws, r4l, r4l, lane, acc2);    // (2,4,4) p3-5
    combo_mp<6,5,9,9,6,3>(ws, r4l, r4l, lane, acc2);    // (2,4,4) p6-8
    combo_mp<5,5,5,9,0,3>(ws, r2l, r4l, lane, acc2);    // (2,2,4) p0-2
    combo_mp<5,5,5,9,3,2>(ws, r2l, r4l, lane, acc2);    // (2,2,4) p3-4
  } else if (wave == 2) {
    combo_mp<9,9,5,9,0,2>(ws, r2l, r4l, lane, acc4);    // (4,2,4) p0-1
    combo_mp<9,9,5,9,2,2>(ws, r2l, r4l, lane, acc4);    // (4,2,4) p2-3
    combo_mp<9,9,5,9,4,1>(ws, r2l, r4l, lane, acc4);    // (4,2,4) p4
    combo_mp<8,9,5,5,0,2>(ws, r2l, r2l, lane, acc4);    // (4,2,2) p0-1
    combo_mp<8,9,5,5,2,2>(ws, r2l, r2l, lane, acc4);    // (4,2,2) p2-3
  } else {
    combo_mp<10,9,9,9,6,1>(ws, r4l, r4l, lane, acc4);   // (4,4,4) p6
    combo_mp<10,9,9,9,7,1>(ws, r4l, r4l, lane, acc4);   // (4,4,4) p7
    combo_mp<10,9,9,9,8,1>(ws, r4l, r4l, lane, acc4);   // (4,4,4) p8
    combo_mp<8,9,5,5,4,1>(ws, r2l, r2l, lane, acc4);    // (4,2,2) p4
    combo_mp<7,9,1,9,0,1>(ws, r0, r4l, lane, acc4);     // (4,0,4)
    combo_mp<4,5,5,5,0,1>(ws, r2l, r2l, lane, acc2);    // (2,2,2) p0
    combo_mp<4,5,5,5,1,1>(ws, r2l, r2l, lane, acc2);    // (2,2,2) p1
    combo_mp<4,5,5,5,2,1>(ws, r2l, r2l, lane, acc2);    // (2,2,2) p2
    combo_mp<4,5,5,5,3,1>(ws, r2l, r2l, lane, acc2);    // (2,2,2) p3
    combo_mp<4,5,5,5,4,1>(ws, r2l, r2l, lane, acc2);    // (2,2,2) p4
    combo_mp<3,5,1,5,0,1>(ws, r0, r2l, lane, acc2);     // (2,0,2)
    combo_mp<2,1,9,9,0,9>(ws, r4l, r4l, lane, acc0);    // (0,4,4) (D=1: tiny)
    combo_mp<1,1,5,5,0,5>(ws, r2l, r2l, lane, acc0);    // (0,2,2)
    combo_mp<0,1,1,1,0,1>(ws, r0, r0, lane, acc0);      // (0,0,0)
  }

  // merge partial accumulators through LDS (staging data is dead now)
  __syncthreads();
  if (wave == 0) {
    lds[lane] = acc0[0];
    #pragma unroll
    for (int e = 0; e < 25; ++e) lds[(1 + e) * 65 + lane] = acc2[e];
    #pragma unroll
    for (int e = 0; e < 81; ++e) lds[(26 + e) * 65 + lane] = acc4[e];
  }
  __syncthreads();
  if (wave == 1) {
    lds[lane] += acc0[0];
    #pragma unroll
    for (int e = 0; e < 25; ++e) lds[(1 + e) * 65 + lane] += acc2[e];
    #pragma unroll
    for (int e = 0; e < 81; ++e) lds[(26 + e) * 65 + lane] += acc4[e];
  }
  __syncthreads();
  if (wave == 2) {
    lds[lane] += acc0[0];
    #pragma unroll
    for (int e = 0; e < 25; ++e) lds[(1 + e) * 65 + lane] += acc2[e];
    #pragma unroll
    for (int e = 0; e < 81; ++e) lds[(26 + e) * 65 + lane] += acc4[e];
  }
  __syncthreads();
  if (wave == 3) {
    lds[lane] += acc0[0];
    #pragma unroll
    for (int e = 0; e < 25; ++e) lds[(1 + e) * 65 + lane] += acc2[e];
    #pragma unroll
    for (int e = 0; e < 81; ++e) lds[(26 + e) * 65 + lane] += acc4[e];
  }
  __syncthreads();

  // coalesced stores: rh_n[0] | rh_n[2] | rh_n[4]
  if (tid < 64) out[site0 + tid] = lds[tid];
  for (int f = tid; f < 1600; f += 256) {
    int s = f / 25, e = f - s * 25;
    out[65536 + blk * 1600 + f] = lds[(1 + e) * 65 + s];
  }
  for (int f = tid; f < 5184; f += 256) {
    int s = f / 81, e = f - s * 81;
    out[1703936 + blk * 5184 + f] = lds[(26 + e) * 65 + s];
  }

  // rotation-invariant features
  if (tid < 64) {
    int site = site0 + tid;
    int nn = site >> 12, abc = site & 4095;
    float v0 = lds[tid];
    float f0 = v0 * v0;
    float s2 = 0.f;
    #pragma unroll
    for (int e = 0; e < 25; ++e) { float v = lds[(1 + e) * 65 + tid]; s2 = fmaf(v, v, s2); }
    float s4 = 0.f;
    #pragma unroll
    for (int e = 0; e < 81; ++e) { float v = lds[(26 + e) * 65 + tid]; s4 = fmaf(v, v, s4); }
    const float PI8 = 78.95683520871486f;  // 8*pi^2
    int base = 7012352 + nn * 12352 + 64;
    out[base + abc] = PI8 * f0;
    out[base + 4096 + abc] = (PI8 / 5.f) * s2;
    out[base + 8192 + abc] = (PI8 / 9.f) * s4;
  }
}

extern "C" void kernel_launch(void* const* d_in, const int* in_sizes, int n_in,
                              void* d_out, int out_size, void* d_ws, size_t ws_size,
                              hipStream_t stream) {
  const float* rh0 = (const float*)d_in[0];
  const float* rh2 = (const float*)d_in[1];
  const float* rh4 = (const float*)d_in[2];
  const float* feats = (const float*)d_in[3];
  float* out = (float*)d_out;
  float* ws = (float*)d_ws;
  setup_copy<<<2, 256, 0, stream>>>(ws, feats, out);
  quad_main<<<1024, 256, 0, stream>>>(rh0, rh2, rh4, ws, out);
}